// Round 28
// baseline (114.997 us; speedup 1.0000x reference)
//
#include <hip/hip_runtime.h>
#include <hip/hip_bf16.h>

// Deformable 2D conv, FUSED single-kernel. B=8 H=128 W=128 C=64 F=128 K=3.
// R28 = R27 + phase-1 2-pixel weight-sharing: each thread's two items
// (pix, pix+32) share c4 and ALL weight rows -> read each wL float4 once
// (180 -> 99 ds_read_b128/thread; LDS pipe 14.4 -> ~8us/CU). acc[2][9]=18
// regs (vs R24's 36 that blew regalloc).
// K0 pack: cW->cWb bf16 [ks][q4][f][jj]; oW->oWt t-major [(pq*9+t)*64+ch].
// K1 fused, LDS 78336 B (2 blocks/CU):
//   region A [0,73728): ph0/1 = wL(20736) + halo fp32 3x66x64 (50688)
//                        + offs_s(2304 tail);  ph3+ = smpB bf16 [64][576].
//   ph0 stage wL + zero-padded halo; ph1 offsets fp32 (2-px tiled);
//   ph2 meta; ph3 gather (6x3 pinned batches, XOR-swizzled smpB);
//   ph4 MFMA (wave = unique 16-f slice, 4 m-tiles, B prefetch);
//   ph5 LDS-staged coalesced epilogue.
// Fallback (small ws): R8-style fused kernel.
//
// MFMA 16x16x32 bf16 (m89/m91): A row=lane&15, k=8*(lane>>4)+j; B col same;
// D col=lane&15, row=4*(lane>>4)+reg.
// NOTE: offsets must stay fp32 (bf16 offsets flip floor() at the clamp
// discontinuities -> R5 failed at 2.39).

typedef __attribute__((ext_vector_type(8))) short short8;
typedef __attribute__((ext_vector_type(4))) float f32x4;

#define CWB_BYTES  (18 * 4 * 128 * 8 * 2)   // 147456
#define OWT_OFF    CWB_BYTES
#define OWT_BYTES  (9 * 9 * 64 * 4)         // 20736
#define WS_NEED    (OWT_OFF + OWT_BYTES)    // 168192

#define WL_OFF    0        // 20736 B (floats [81*64], t-major)
#define HALO_OFF  20736    // 50688 B (floats [3*66][64])
#define OFFS_S_OFF 71424   // 2304 B (floats [64*9])

__device__ __forceinline__ unsigned short f2bf(float f) {  // RNE
  union { float f; unsigned u; } v; v.f = f;
  unsigned r = v.u + 0x7fffu + ((v.u >> 16) & 1u);
  return (unsigned short)(r >> 16);
}

__device__ __forceinline__ unsigned pk2bf(float a, float b) {  // v_cvt_pk RNE
  __hip_bfloat162 h = __float22bfloat162_rn(make_float2(a, b));
  union { __hip_bfloat162 h; unsigned u; } c; c.h = h;
  return c.u;
}

// ---- K0: weight pack ------------------------------------------------------
__global__ __launch_bounds__(256) void pack_kernel(
    const float* __restrict__ cW, const float* __restrict__ oW,
    unsigned short* __restrict__ cWb, float* __restrict__ oWt) {
  const int t = blockIdx.x * 256 + threadIdx.x;
  if (t < 73728) {  // cWb: t = k*128 + f
    const int k = t >> 7, f = t & 127;
    const int ks = k >> 5, q4 = (k >> 3) & 3, jj = k & 7;
    cWb[(size_t)(((ks * 4 + q4) * 128 + f) * 8 + jj)] = f2bf(cW[t]);
  }
  if (t < 5184) {  // oWt[(pq*9+tt)*64+ch] = oW[(pq*64+ch)*9+tt]
    const int pq = t / 576;
    const int r = t - pq * 576;
    const int tt = r >> 6;
    const int ch = r & 63;
    oWt[t] = oW[(size_t)(pq * 64 + ch) * 9 + tt];
  }
}

// ---- K1: fused offsets + gather + MFMA, block = 64 px --------------------
__global__ __launch_bounds__(512, 2) void fused_kernel(
    const float* __restrict__ x, const float* __restrict__ oWt,
    const float* __restrict__ ob, const float* __restrict__ cb,
    float* __restrict__ out, const unsigned short* __restrict__ cWb) {
  __shared__ __align__(16) char lds[73728];  // region A
  __shared__ float offw[576];  // w1 per (pix,tap)
  __shared__ int gpk[576];     // base byte offset (256-aligned) | delta bit

  float* const wL = (float*)(lds + WL_OFF);
  float* const halo = (float*)(lds + HALO_OFF);   // [hr=3*66][64]
  float* const offs_s = (float*)(lds + OFFS_S_OFF);

  const int tid = threadIdx.x;
  const int hwbid = blockIdx.x;
  const int bid = ((hwbid & 7) << 8) | (hwbid >> 3);  // XCD k -> batch k
  const int j0 = (bid & 1) << 6;      // 2 strips of 64 px per row
  const int i = (bid >> 1) & 127;
  const int b = bid >> 8;
  const float* xb = x + ((size_t)b << 20);

  const int lane = tid & 63;
  const int wv = tid >> 6;

  // ---- Phase 0: stage wL (1296 f4) and zero-padded halo (3168 f4) ----
  for (int it = tid; it < 1296; it += 512)
    ((float4*)wL)[it] = ((const float4*)oWt)[it];
  for (int it = tid; it < 3 * 66 * 16; it += 512) {
    const int c4 = it & 15;
    const int hr = it >> 4;       // r*66 + cc
    const int cc = hr % 66;
    const int r = hr / 66;
    const int grow = i + r - 1;
    const int gcol = j0 + cc - 1;
    float4 v = make_float4(0.f, 0.f, 0.f, 0.f);
    if (grow >= 0 && grow <= 127 && gcol >= 0 && gcol <= 127)
      v = ((const float4*)(xb + (((grow << 7) + gcol) << 6)))[c4];
    ((float4*)halo)[it] = v;      // contiguous [hr][c4]
  }
  __syncthreads();

  // ---- Phase 1: offsets conv fp32, 2-pixel weight-sharing ----
  {
    const int pix0 = tid >> 4;   // 0..31; second pixel = pix0 + 32
    const int c4 = tid & 15;
    float acc0[9], acc1[9];
#pragma unroll
    for (int t = 0; t < 9; ++t) { acc0[t] = 0.f; acc1[t] = 0.f; }
#pragma unroll
    for (int pq = 0; pq < 9; ++pq) {
      const int p = pq / 3, q = pq - p * 3;
      const float4 v0 =
          ((const float4*)(halo + ((p * 66 + pix0 + q) << 6)))[c4];
      const float4 v1 =
          ((const float4*)(halo + ((p * 66 + pix0 + 32 + q) << 6)))[c4];
      const float4* wrow = (const float4*)wL + pq * 9 * 16 + c4;
#pragma unroll
      for (int t = 0; t < 9; ++t) {
        const float4 w4 = wrow[t * 16];  // read ONCE, used for both pixels
        acc0[t] += v0.x * w4.x + v0.y * w4.y + v0.z * w4.z + v0.w * w4.w;
        acc1[t] += v1.x * w4.x + v1.y * w4.y + v1.z * w4.z + v1.w * w4.w;
      }
    }
#pragma unroll
    for (int t = 0; t < 9; ++t) {
      acc0[t] += __shfl_xor(acc0[t], 1);
      acc0[t] += __shfl_xor(acc0[t], 2);
      acc0[t] += __shfl_xor(acc0[t], 4);
      acc0[t] += __shfl_xor(acc0[t], 8);
      acc1[t] += __shfl_xor(acc1[t], 1);
      acc1[t] += __shfl_xor(acc1[t], 2);
      acc1[t] += __shfl_xor(acc1[t], 4);
      acc1[t] += __shfl_xor(acc1[t], 8);
    }
    if (c4 == 0) {
#pragma unroll
      for (int t = 0; t < 9; ++t) {
        offs_s[pix0 * 9 + t] = acc0[t] + ob[t];
        offs_s[(pix0 + 32) * 9 + t] = acc1[t] + ob[t];
      }
    }
  }
  __syncthreads();

  // ---- Phase 2: meta (R23-exact, source = offs_s) ----
  for (int item = tid; item < 576; item += 512) {
    const int pix = item / 9;
    const int tap = item - pix * 9;
    const float off = offs_s[item];
    const int p = tap / 3;
    const int q = tap - p * 3;
    int yy = i + p - 1;
    yy = yy < 0 ? 0 : (yy > 127 ? 127 : yy);
    const float xf = (float)(j0 + pix + q - 1) + off;
    const float x0f = floorf(xf);
    const float w1 = xf - x0f;  // weight from UNclipped floor (matches ref)
    int x0i = (int)x0f;
    x0i = x0i < 0 ? 0 : (x0i > 127 ? 127 : x0i);
    const int x1i = (x0i + 1 > 127) ? 127 : x0i + 1;
    gpk[item] = ((((yy << 7) + x0i) << 8)) | (x1i - x0i);
    offw[item] = w1;
  }
  __syncthreads();  // offs_s consumed; region A free for smpB

  // ---- Phase 3: gather; 6 batches x (3 items -> 6 loads) ----
#pragma unroll
  for (int batch = 0; batch < 6; ++batch) {
    int a0_[3], a1_[3], sb[3];
    float sw1[3];
#pragma unroll
    for (int s = 0; s < 3; ++s) {
      const int idx = tid + (batch * 3 + s) * 512;
      const int c4 = idx & 15;
      const int pair = idx >> 4;        // 0..575
      const int g = gpk[pair];
      sw1[s] = offw[pair];
      const int base = g & ~255;
      a0_[s] = base + (c4 << 4);
      a1_[s] = a0_[s] + ((g & 1) << 8);
      const int pix8 = (pair / 9) & 7;
      sb[s] = ((pair << 7) + (c4 << 3)) ^ (pix8 << 4);
    }
    float4 s0[3], s1[3];
#pragma unroll
    for (int s = 0; s < 3; ++s) {
      s0[s] = *(const float4*)((const char*)xb + a0_[s]);
      s1[s] = *(const float4*)((const char*)xb + a1_[s]);
    }
    asm volatile("" :: "v"(s0[0].x), "v"(s0[1].x), "v"(s0[2].x),
                       "v"(s1[0].x), "v"(s1[1].x), "v"(s1[2].x));
    __builtin_amdgcn_sched_barrier(0);
#pragma unroll
    for (int s = 0; s < 3; ++s) {
      const float w1 = sw1[s];
      uint2 pk;
      pk.x = pk2bf(s0[s].x + w1 * (s1[s].x - s0[s].x),
                   s0[s].y + w1 * (s1[s].y - s0[s].y));
      pk.y = pk2bf(s0[s].z + w1 * (s1[s].z - s0[s].z),
                   s0[s].w + w1 * (s1[s].w - s0[s].w));
      *(uint2*)(lds + sb[s]) = pk;
    }
  }
  __syncthreads();

  // ---- Phase 4: MFMA. Wave w: unique f-slice f0=16w, all 4 m-tiles ----
  const int f0 = wv << 4;
  const int colf = lane & 15;
  const int q4 = lane >> 4;
  f32x4 a0 = {0.f, 0.f, 0.f, 0.f}, a1 = a0, a2 = a0, a3 = a0;
  short8 bf;
  {
    const unsigned short* wb = cWb + (size_t)((q4 * 128 + f0 + colf) * 8);
    bf = *(const short8*)wb;
  }
  for (int ks = 0; ks < 18; ++ks) {
    const int aoff = (colf * 1152 + ks * 64 + q4 * 16) ^ ((colf & 7) << 4);
    const short8 af0 = *(const short8*)(lds + aoff);
    const short8 af1 = *(const short8*)(lds + aoff + 16 * 1152);
    const short8 af2 = *(const short8*)(lds + aoff + 32 * 1152);
    const short8 af3 = *(const short8*)(lds + aoff + 48 * 1152);
    short8 nb;
    if (ks < 17) {
      nb = *(const short8*)(cWb +
            (size_t)((((ks + 1) * 4 + q4) * 128 + f0 + colf) * 8));
    }
    a0 = __builtin_amdgcn_mfma_f32_16x16x32_bf16(bf, af0, a0, 0, 0, 0);
    a1 = __builtin_amdgcn_mfma_f32_16x16x32_bf16(bf, af1, a1, 0, 0, 0);
    a2 = __builtin_amdgcn_mfma_f32_16x16x32_bf16(bf, af2, a2, 0, 0, 0);
    a3 = __builtin_amdgcn_mfma_f32_16x16x32_bf16(bf, af3, a3, 0, 0, 0);
    if (ks < 17) bf = nb;
  }
  __syncthreads();  // phase-4 LDS reads done; reuse lds for out staging

  // ---- Phase 5: epilogue, stage [64 pix][132] fp32, coalesced stores ----
  float* const outS = (float*)lds;
  {
    const float4 cbv = *(const float4*)(cb + f0 + q4 * 4);
    float4 r;
    r.x = a0[0] + cbv.x; r.y = a0[1] + cbv.y;
    r.z = a0[2] + cbv.z; r.w = a0[3] + cbv.w;
    *(float4*)(outS + (colf) * 132 + f0 + q4 * 4) = r;
    r.x = a1[0] + cbv.x; r.y = a1[1] + cbv.y;
    r.z = a1[2] + cbv.z; r.w = a1[3] + cbv.w;
    *(float4*)(outS + (16 + colf) * 132 + f0 + q4 * 4) = r;
    r.x = a2[0] + cbv.x; r.y = a2[1] + cbv.y;
    r.z = a2[2] + cbv.z; r.w = a2[3] + cbv.w;
    *(float4*)(outS + (32 + colf) * 132 + f0 + q4 * 4) = r;
    r.x = a3[0] + cbv.x; r.y = a3[1] + cbv.y;
    r.z = a3[2] + cbv.z; r.w = a3[3] + cbv.w;
    *(float4*)(outS + (48 + colf) * 132 + f0 + q4 * 4) = r;
  }
  __syncthreads();
  float4* og = (float4*)(out + (((size_t)((b << 14) | (i << 7) | j0)) << 7));
#pragma unroll
  for (int r = 0; r < 4; ++r) {
    const int f4i = r * 512 + tid;
    const int pp = f4i >> 5, ff = f4i & 31;
    og[pp * 32 + ff] = *(const float4*)(outS + pp * 132 + ff * 4);
  }
}

// ---- Fallback: fused kernel (small ws, no packing) ----
__global__ __launch_bounds__(512, 8) void fused_deform_kernel(
    const float* __restrict__ x, const float* __restrict__ oW,
    const float* __restrict__ ob, const float* __restrict__ cW,
    const float* __restrict__ cb, float* __restrict__ out) {
  __shared__ __align__(16) char lds[32 * 576 * 2];
  __shared__ float offs_s[288];
  float* const xtile = (float*)lds;  // [102 rows][stride 68]

  const int tid = threadIdx.x;
  const int bid = blockIdx.x;
  const int j0 = (bid & 3) << 5;
  const int i = (bid >> 2) & 127;
  const int b = bid >> 9;
  const float* xb = x + ((size_t)b << 20);
  const int lane = tid & 63;
  const int wv = tid >> 6;

  for (int t = tid; t < 3 * 34 * 16; t += 512) {
    const int c4 = t & 15;
    const int cc = (t >> 4) % 34;
    const int r = (t >> 4) / 34;
    const int row = i + r - 1;
    const int col = j0 + cc - 1;
    float4 v = make_float4(0.f, 0.f, 0.f, 0.f);
    if (row >= 0 && row <= 127 && col >= 0 && col <= 127)
      v = ((const float4*)(xb + (((row << 7) + col) << 6)))[c4];
    *(float4*)(xtile + (r * 34 + cc) * 68 + c4 * 4) = v;
  }
  __syncthreads();

  for (int t = tid; t < 576; t += 512) {
    const int half = t & 1;
    const int item = t >> 1;
    const int ochan = item % 9;
    const int pix = item / 9;
    const int c4base = half << 3;
    f32x4 acc = {0.f, 0.f, 0.f, 0.f};
#pragma unroll
    for (int pq = 0; pq < 9; ++pq) {
      const int p = pq / 3, q = pq - p * 3;
      const float4* xr = (const float4*)(xtile + (p * 34 + pix + q) * 68) + c4base;
      const float* wr = oW + (size_t)(pq * 64 + c4base * 4) * 9 + ochan;
#pragma unroll
      for (int c4 = 0; c4 < 8; ++c4) {
        const float4 v = xr[c4];
        acc.x += v.x * wr[(c4 * 4 + 0) * 9];
        acc.y += v.y * wr[(c4 * 4 + 1) * 9];
        acc.z += v.z * wr[(c4 * 4 + 2) * 9];
        acc.w += v.w * wr[(c4 * 4 + 3) * 9];
      }
    }
    float s = (acc.x + acc.y) + (acc.z + acc.w);
    s += __shfl_xor(s, 1);
    if (!half) offs_s[item] = s + ob[ochan];
  }
  __syncthreads();

  for (int it = tid; it < 32 * 9 * 16; it += 512) {
    const int c4 = it & 15;
    const int tmp = it >> 4;
    const int tap = tmp % 9;
    const int pix = tmp / 9;
    const int j = j0 + pix;
    const float off = offs_s[pix * 9 + tap];
    const int p = tap / 3;
    const int q = tap - p * 3;
    int yy = i + p - 1;
    yy = yy < 0 ? 0 : (yy > 127 ? 127 : yy);
    const float xf = (float)(j + q - 1) + off;
    const float x0f = floorf(xf);
    const float w1 = xf - x0f;
    int x0i = (int)x0f;
    x0i = x0i < 0 ? 0 : (x0i > 127 ? 127 : x0i);
    const int x1i = (x0i + 1 > 127) ? 127 : x0i + 1;
    const float4 s0 = ((const float4*)(xb + (((yy << 7) + x0i) << 6)))[c4];
    const float4 s1 = ((const float4*)(xb + (((yy << 7) + x1i) << 6)))[c4];
    const float w0 = 1.0f - w1;
    const int boff = (pix * 1152 + tap * 128 + c4 * 8) ^ ((pix & 7) << 4);
    uint2 pk;
    pk.x = (unsigned)f2bf(s0.x * w0 + s1.x * w1) |
           ((unsigned)f2bf(s0.y * w0 + s1.y * w1) << 16);
    pk.y = (unsigned)f2bf(s0.z * w0 + s1.z * w1) |
           ((unsigned)f2bf(s0.w * w0 + s1.w * w1) << 16);
    *(uint2*)(lds + boff) = pk;
  }
  __syncthreads();

  const int m = wv & 1;
  const int f0 = (wv >> 1) << 5;
  const int colf = lane & 15;
  const int q4 = lane >> 4;
  const int pixr = m * 16 + colf;
  f32x4 a0 = {0.f, 0.f, 0.f, 0.f}, a1 = a0;
  for (int ks = 0; ks < 18; ++ks) {
    const int aoff = (pixr * 1152 + ks * 64 + q4 * 16) ^ ((pixr & 7) << 4);
    const short8 af = *(const short8*)(lds + aoff);
    short8 bf0, bf1;
    const float* wp = cW + (size_t)(ks * 32 + q4 * 8) * 128 + f0 + colf;
#pragma unroll
    for (int jj = 0; jj < 8; ++jj) bf0[jj] = (short)f2bf(wp[jj * 128]);
#pragma unroll
    for (int jj = 0; jj < 8; ++jj) bf1[jj] = (short)f2bf(wp[jj * 128 + 16]);
    a0 = __builtin_amdgcn_mfma_f32_16x16x32_bf16(bf0, af, a0, 0, 0, 0);
    a1 = __builtin_amdgcn_mfma_f32_16x16x32_bf16(bf1, af, a1, 0, 0, 0);
  }

  const float cb0s = cb[f0 + colf];
  const float cb1s = cb[f0 + 16 + colf];
  float* obase = out + (((size_t)((b << 14) | (i << 7) | j0)) << 7);
#pragma unroll
  for (int reg = 0; reg < 4; ++reg) {
    float* r = obase + (size_t)(m * 16 + q4 * 4 + reg) * 128;
    r[f0 + colf] = a0[reg] + cb0s;
    r[f0 + 16 + colf] = a1[reg] + cb1s;
  }
}

extern "C" void kernel_launch(void* const* d_in, const int* in_sizes, int n_in,
                              void* d_out, int out_size, void* d_ws, size_t ws_size,
                              hipStream_t stream) {
  const float* x = (const float*)d_in[0];
  const float* oW = (const float*)d_in[1];
  const float* ob = (const float*)d_in[2];
  const float* cW = (const float*)d_in[3];
  const float* cb = (const float*)d_in[4];
  float* out = (float*)d_out;

  if (ws_size >= WS_NEED) {
    unsigned short* cWb = (unsigned short*)d_ws;
    float* oWt = (float*)((char*)d_ws + OWT_OFF);
    hipLaunchKernelGGL(pack_kernel, dim3(288), dim3(256), 0, stream,
                       cW, oW, cWb, oWt);
    hipLaunchKernelGGL(fused_kernel, dim3(2048), dim3(512), 0, stream,
                       x, oWt, ob, cb, out, cWb);
  } else {
    hipLaunchKernelGGL(fused_deform_kernel, dim3(4096), dim3(512), 0, stream,
                       x, oW, ob, cW, cb, out);
  }
}

// Round 29
// 90.679 us; speedup vs baseline: 1.2682x; 1.2682x over previous
//
#include <hip/hip_runtime.h>
#include <hip/hip_bf16.h>

// Deformable 2D conv, FUSED single-kernel. B=8 H=128 W=128 C=64 F=128 K=3.
// FINAL = R27-exact (measured 90.7us total; 10x over 903us R4 baseline).
// R28's 2-px weight-sharing pushed VGPR 60->120 -> occ 21% -> 115us: the
// phase-1 LDS saving cannot pay for an occupancy halving. Reverted.
// K0 pack: cW->cWb bf16 [ks][q4][f][jj]; oW->oWt t-major [(pq*9+t)*64+ch].
// K1 fused, LDS 78336 B (2 blocks/CU, VGPR 60):
//   ph0 stage wL + zero-padded fp32 halo 3x66x64 (contiguous b128);
//   ph1 offsets conv fp32 (thread=(pix,c4) x2 sequential items, shfl_xor
//       reduce) -> offs_s in LDS (no HBM round-trip);
//   ph2 meta: packed gpk (base|delta-bit) + offw (UNclipped-floor w1);
//   ph3 gather: 6x3 liveness-pinned batches -> XOR-swizzled smpB bf16;
//   ph4 MFMA 16x16x32: wave = unique 16-f slice, 4 m-tiles, B prefetch;
//   ph5 LDS-staged coalesced epilogue.
// Fallback (small ws): R8-style fused kernel.
//
// MFMA 16x16x32 bf16 (m89/m91): A row=lane&15, k=8*(lane>>4)+j; B col same;
// D col=lane&15, row=4*(lane>>4)+reg.
// NOTE: offsets must stay fp32 (bf16 offsets flip floor() at the clamp
// discontinuities -> R5 failed at 2.39).

typedef __attribute__((ext_vector_type(8))) short short8;
typedef __attribute__((ext_vector_type(4))) float f32x4;

#define CWB_BYTES  (18 * 4 * 128 * 8 * 2)   // 147456
#define OWT_OFF    CWB_BYTES
#define OWT_BYTES  (9 * 9 * 64 * 4)         // 20736
#define WS_NEED    (OWT_OFF + OWT_BYTES)    // 168192

#define WL_OFF    0        // 20736 B (floats [81*64], t-major)
#define HALO_OFF  20736    // 50688 B (floats [3*66][64])
#define OFFS_S_OFF 71424   // 2304 B (floats [64*9])

__device__ __forceinline__ unsigned short f2bf(float f) {  // RNE
  union { float f; unsigned u; } v; v.f = f;
  unsigned r = v.u + 0x7fffu + ((v.u >> 16) & 1u);
  return (unsigned short)(r >> 16);
}

__device__ __forceinline__ unsigned pk2bf(float a, float b) {  // v_cvt_pk RNE
  __hip_bfloat162 h = __float22bfloat162_rn(make_float2(a, b));
  union { __hip_bfloat162 h; unsigned u; } c; c.h = h;
  return c.u;
}

// ---- K0: weight pack ------------------------------------------------------
__global__ __launch_bounds__(256) void pack_kernel(
    const float* __restrict__ cW, const float* __restrict__ oW,
    unsigned short* __restrict__ cWb, float* __restrict__ oWt) {
  const int t = blockIdx.x * 256 + threadIdx.x;
  if (t < 73728) {  // cWb: t = k*128 + f
    const int k = t >> 7, f = t & 127;
    const int ks = k >> 5, q4 = (k >> 3) & 3, jj = k & 7;
    cWb[(size_t)(((ks * 4 + q4) * 128 + f) * 8 + jj)] = f2bf(cW[t]);
  }
  if (t < 5184) {  // oWt[(pq*9+tt)*64+ch] = oW[(pq*64+ch)*9+tt]
    const int pq = t / 576;
    const int r = t - pq * 576;
    const int tt = r >> 6;
    const int ch = r & 63;
    oWt[t] = oW[(size_t)(pq * 64 + ch) * 9 + tt];
  }
}

// ---- K1: fused offsets + gather + MFMA, block = 64 px --------------------
__global__ __launch_bounds__(512, 2) void fused_kernel(
    const float* __restrict__ x, const float* __restrict__ oWt,
    const float* __restrict__ ob, const float* __restrict__ cb,
    float* __restrict__ out, const unsigned short* __restrict__ cWb) {
  __shared__ __align__(16) char lds[73728];  // region A
  __shared__ float offw[576];  // w1 per (pix,tap)
  __shared__ int gpk[576];     // base byte offset (256-aligned) | delta bit

  float* const wL = (float*)(lds + WL_OFF);
  float* const halo = (float*)(lds + HALO_OFF);   // [hr=3*66][64]
  float* const offs_s = (float*)(lds + OFFS_S_OFF);

  const int tid = threadIdx.x;
  const int hwbid = blockIdx.x;
  const int bid = ((hwbid & 7) << 8) | (hwbid >> 3);  // XCD k -> batch k
  const int j0 = (bid & 1) << 6;      // 2 strips of 64 px per row
  const int i = (bid >> 1) & 127;
  const int b = bid >> 8;
  const float* xb = x + ((size_t)b << 20);

  const int lane = tid & 63;
  const int wv = tid >> 6;

  // ---- Phase 0: stage wL (1296 f4) and zero-padded halo (3168 f4) ----
  for (int it = tid; it < 1296; it += 512)
    ((float4*)wL)[it] = ((const float4*)oWt)[it];
  for (int it = tid; it < 3 * 66 * 16; it += 512) {
    const int c4 = it & 15;
    const int hr = it >> 4;       // r*66 + cc
    const int cc = hr % 66;
    const int r = hr / 66;
    const int grow = i + r - 1;
    const int gcol = j0 + cc - 1;
    float4 v = make_float4(0.f, 0.f, 0.f, 0.f);
    if (grow >= 0 && grow <= 127 && gcol >= 0 && gcol <= 127)
      v = ((const float4*)(xb + (((grow << 7) + gcol) << 6)))[c4];
    ((float4*)halo)[it] = v;      // contiguous [hr][c4]
  }
  __syncthreads();

  // ---- Phase 1: offsets conv fp32. thread=(pix,c4), 2 items ----
#pragma unroll
  for (int half = 0; half < 2; ++half) {
    const int item = tid + half * 512;   // 0..1023
    const int pix = item >> 4;
    const int c4 = item & 15;
    float acc[9];
#pragma unroll
    for (int t = 0; t < 9; ++t) acc[t] = 0.f;
#pragma unroll
    for (int pq = 0; pq < 9; ++pq) {
      const int p = pq / 3, q = pq - p * 3;
      const float4 v = ((const float4*)(halo + ((p * 66 + pix + q) << 6)))[c4];
      const float4* wrow = (const float4*)wL + pq * 9 * 16 + c4;
#pragma unroll
      for (int t = 0; t < 9; ++t) {
        const float4 w4 = wrow[t * 16];
        acc[t] += v.x * w4.x + v.y * w4.y + v.z * w4.z + v.w * w4.w;
      }
    }
#pragma unroll
    for (int t = 0; t < 9; ++t) {
      acc[t] += __shfl_xor(acc[t], 1);
      acc[t] += __shfl_xor(acc[t], 2);
      acc[t] += __shfl_xor(acc[t], 4);
      acc[t] += __shfl_xor(acc[t], 8);
    }
    if (c4 == 0) {
#pragma unroll
      for (int t = 0; t < 9; ++t) offs_s[pix * 9 + t] = acc[t] + ob[t];
    }
  }
  __syncthreads();

  // ---- Phase 2: meta (source = offs_s) ----
  for (int item = tid; item < 576; item += 512) {
    const int pix = item / 9;
    const int tap = item - pix * 9;
    const float off = offs_s[item];
    const int p = tap / 3;
    const int q = tap - p * 3;
    int yy = i + p - 1;
    yy = yy < 0 ? 0 : (yy > 127 ? 127 : yy);
    const float xf = (float)(j0 + pix + q - 1) + off;
    const float x0f = floorf(xf);
    const float w1 = xf - x0f;  // weight from UNclipped floor (matches ref)
    int x0i = (int)x0f;
    x0i = x0i < 0 ? 0 : (x0i > 127 ? 127 : x0i);
    const int x1i = (x0i + 1 > 127) ? 127 : x0i + 1;
    gpk[item] = ((((yy << 7) + x0i) << 8)) | (x1i - x0i);
    offw[item] = w1;
  }
  __syncthreads();  // offs_s consumed; region A free for smpB

  // ---- Phase 3: gather; 6 batches x (3 items -> 6 loads) ----
#pragma unroll
  for (int batch = 0; batch < 6; ++batch) {
    int a0_[3], a1_[3], sb[3];
    float sw1[3];
#pragma unroll
    for (int s = 0; s < 3; ++s) {
      const int idx = tid + (batch * 3 + s) * 512;
      const int c4 = idx & 15;
      const int pair = idx >> 4;        // 0..575
      const int g = gpk[pair];
      sw1[s] = offw[pair];
      const int base = g & ~255;
      a0_[s] = base + (c4 << 4);
      a1_[s] = a0_[s] + ((g & 1) << 8);
      const int pix8 = (pair / 9) & 7;
      sb[s] = ((pair << 7) + (c4 << 3)) ^ (pix8 << 4);
    }
    float4 s0[3], s1[3];
#pragma unroll
    for (int s = 0; s < 3; ++s) {
      s0[s] = *(const float4*)((const char*)xb + a0_[s]);
      s1[s] = *(const float4*)((const char*)xb + a1_[s]);
    }
    asm volatile("" :: "v"(s0[0].x), "v"(s0[1].x), "v"(s0[2].x),
                       "v"(s1[0].x), "v"(s1[1].x), "v"(s1[2].x));
    __builtin_amdgcn_sched_barrier(0);
#pragma unroll
    for (int s = 0; s < 3; ++s) {
      const float w1 = sw1[s];
      uint2 pk;
      pk.x = pk2bf(s0[s].x + w1 * (s1[s].x - s0[s].x),
                   s0[s].y + w1 * (s1[s].y - s0[s].y));
      pk.y = pk2bf(s0[s].z + w1 * (s1[s].z - s0[s].z),
                   s0[s].w + w1 * (s1[s].w - s0[s].w));
      *(uint2*)(lds + sb[s]) = pk;
    }
  }
  __syncthreads();

  // ---- Phase 4: MFMA. Wave w: unique f-slice f0=16w, all 4 m-tiles ----
  const int f0 = wv << 4;
  const int colf = lane & 15;
  const int q4 = lane >> 4;
  f32x4 a0 = {0.f, 0.f, 0.f, 0.f}, a1 = a0, a2 = a0, a3 = a0;
  short8 bf;
  {
    const unsigned short* wb = cWb + (size_t)((q4 * 128 + f0 + colf) * 8);
    bf = *(const short8*)wb;
  }
  for (int ks = 0; ks < 18; ++ks) {
    const int aoff = (colf * 1152 + ks * 64 + q4 * 16) ^ ((colf & 7) << 4);
    const short8 af0 = *(const short8*)(lds + aoff);
    const short8 af1 = *(const short8*)(lds + aoff + 16 * 1152);
    const short8 af2 = *(const short8*)(lds + aoff + 32 * 1152);
    const short8 af3 = *(const short8*)(lds + aoff + 48 * 1152);
    short8 nb;
    if (ks < 17) {
      nb = *(const short8*)(cWb +
            (size_t)((((ks + 1) * 4 + q4) * 128 + f0 + colf) * 8));
    }
    a0 = __builtin_amdgcn_mfma_f32_16x16x32_bf16(bf, af0, a0, 0, 0, 0);
    a1 = __builtin_amdgcn_mfma_f32_16x16x32_bf16(bf, af1, a1, 0, 0, 0);
    a2 = __builtin_amdgcn_mfma_f32_16x16x32_bf16(bf, af2, a2, 0, 0, 0);
    a3 = __builtin_amdgcn_mfma_f32_16x16x32_bf16(bf, af3, a3, 0, 0, 0);
    if (ks < 17) bf = nb;
  }
  __syncthreads();  // phase-4 LDS reads done; reuse lds for out staging

  // ---- Phase 5: epilogue, stage [64 pix][132] fp32, coalesced stores ----
  float* const outS = (float*)lds;
  {
    const float4 cbv = *(const float4*)(cb + f0 + q4 * 4);
    float4 r;
    r.x = a0[0] + cbv.x; r.y = a0[1] + cbv.y;
    r.z = a0[2] + cbv.z; r.w = a0[3] + cbv.w;
    *(float4*)(outS + (colf) * 132 + f0 + q4 * 4) = r;
    r.x = a1[0] + cbv.x; r.y = a1[1] + cbv.y;
    r.z = a1[2] + cbv.z; r.w = a1[3] + cbv.w;
    *(float4*)(outS + (16 + colf) * 132 + f0 + q4 * 4) = r;
    r.x = a2[0] + cbv.x; r.y = a2[1] + cbv.y;
    r.z = a2[2] + cbv.z; r.w = a2[3] + cbv.w;
    *(float4*)(outS + (32 + colf) * 132 + f0 + q4 * 4) = r;
    r.x = a3[0] + cbv.x; r.y = a3[1] + cbv.y;
    r.z = a3[2] + cbv.z; r.w = a3[3] + cbv.w;
    *(float4*)(outS + (48 + colf) * 132 + f0 + q4 * 4) = r;
  }
  __syncthreads();
  float4* og = (float4*)(out + (((size_t)((b << 14) | (i << 7) | j0)) << 7));
#pragma unroll
  for (int r = 0; r < 4; ++r) {
    const int f4i = r * 512 + tid;
    const int pp = f4i >> 5, ff = f4i & 31;
    og[pp * 32 + ff] = *(const float4*)(outS + pp * 132 + ff * 4);
  }
}

// ---- Fallback: fused kernel (small ws, no packing) ----
__global__ __launch_bounds__(512, 8) void fused_deform_kernel(
    const float* __restrict__ x, const float* __restrict__ oW,
    const float* __restrict__ ob, const float* __restrict__ cW,
    const float* __restrict__ cb, float* __restrict__ out) {
  __shared__ __align__(16) char lds[32 * 576 * 2];
  __shared__ float offs_s[288];
  float* const xtile = (float*)lds;  // [102 rows][stride 68]

  const int tid = threadIdx.x;
  const int bid = blockIdx.x;
  const int j0 = (bid & 3) << 5;
  const int i = (bid >> 2) & 127;
  const int b = bid >> 9;
  const float* xb = x + ((size_t)b << 20);
  const int lane = tid & 63;
  const int wv = tid >> 6;

  for (int t = tid; t < 3 * 34 * 16; t += 512) {
    const int c4 = t & 15;
    const int cc = (t >> 4) % 34;
    const int r = (t >> 4) / 34;
    const int row = i + r - 1;
    const int col = j0 + cc - 1;
    float4 v = make_float4(0.f, 0.f, 0.f, 0.f);
    if (row >= 0 && row <= 127 && col >= 0 && col <= 127)
      v = ((const float4*)(xb + (((row << 7) + col) << 6)))[c4];
    *(float4*)(xtile + (r * 34 + cc) * 68 + c4 * 4) = v;
  }
  __syncthreads();

  for (int t = tid; t < 576; t += 512) {
    const int half = t & 1;
    const int item = t >> 1;
    const int ochan = item % 9;
    const int pix = item / 9;
    const int c4base = half << 3;
    f32x4 acc = {0.f, 0.f, 0.f, 0.f};
#pragma unroll
    for (int pq = 0; pq < 9; ++pq) {
      const int p = pq / 3, q = pq - p * 3;
      const float4* xr = (const float4*)(xtile + (p * 34 + pix + q) * 68) + c4base;
      const float* wr = oW + (size_t)(pq * 64 + c4base * 4) * 9 + ochan;
#pragma unroll
      for (int c4 = 0; c4 < 8; ++c4) {
        const float4 v = xr[c4];
        acc.x += v.x * wr[(c4 * 4 + 0) * 9];
        acc.y += v.y * wr[(c4 * 4 + 1) * 9];
        acc.z += v.z * wr[(c4 * 4 + 2) * 9];
        acc.w += v.w * wr[(c4 * 4 + 3) * 9];
      }
    }
    float s = (acc.x + acc.y) + (acc.z + acc.w);
    s += __shfl_xor(s, 1);
    if (!half) offs_s[item] = s + ob[ochan];
  }
  __syncthreads();

  for (int it = tid; it < 32 * 9 * 16; it += 512) {
    const int c4 = it & 15;
    const int tmp = it >> 4;
    const int tap = tmp % 9;
    const int pix = tmp / 9;
    const int j = j0 + pix;
    const float off = offs_s[pix * 9 + tap];
    const int p = tap / 3;
    const int q = tap - p * 3;
    int yy = i + p - 1;
    yy = yy < 0 ? 0 : (yy > 127 ? 127 : yy);
    const float xf = (float)(j + q - 1) + off;
    const float x0f = floorf(xf);
    const float w1 = xf - x0f;
    int x0i = (int)x0f;
    x0i = x0i < 0 ? 0 : (x0i > 127 ? 127 : x0i);
    const int x1i = (x0i + 1 > 127) ? 127 : x0i + 1;
    const float4 s0 = ((const float4*)(xb + (((yy << 7) + x0i) << 6)))[c4];
    const float4 s1 = ((const float4*)(xb + (((yy << 7) + x1i) << 6)))[c4];
    const float w0 = 1.0f - w1;
    const int boff = (pix * 1152 + tap * 128 + c4 * 8) ^ ((pix & 7) << 4);
    uint2 pk;
    pk.x = (unsigned)f2bf(s0.x * w0 + s1.x * w1) |
           ((unsigned)f2bf(s0.y * w0 + s1.y * w1) << 16);
    pk.y = (unsigned)f2bf(s0.z * w0 + s1.z * w1) |
           ((unsigned)f2bf(s0.w * w0 + s1.w * w1) << 16);
    *(uint2*)(lds + boff) = pk;
  }
  __syncthreads();

  const int m = wv & 1;
  const int f0 = (wv >> 1) << 5;
  const int colf = lane & 15;
  const int q4 = lane >> 4;
  const int pixr = m * 16 + colf;
  f32x4 a0 = {0.f, 0.f, 0.f, 0.f}, a1 = a0;
  for (int ks = 0; ks < 18; ++ks) {
    const int aoff = (pixr * 1152 + ks * 64 + q4 * 16) ^ ((pixr & 7) << 4);
    const short8 af = *(const short8*)(lds + aoff);
    short8 bf0, bf1;
    const float* wp = cW + (size_t)(ks * 32 + q4 * 8) * 128 + f0 + colf;
#pragma unroll
    for (int jj = 0; jj < 8; ++jj) bf0[jj] = (short)f2bf(wp[jj * 128]);
#pragma unroll
    for (int jj = 0; jj < 8; ++jj) bf1[jj] = (short)f2bf(wp[jj * 128 + 16]);
    a0 = __builtin_amdgcn_mfma_f32_16x16x32_bf16(bf0, af, a0, 0, 0, 0);
    a1 = __builtin_amdgcn_mfma_f32_16x16x32_bf16(bf1, af, a1, 0, 0, 0);
  }

  const float cb0s = cb[f0 + colf];
  const float cb1s = cb[f0 + 16 + colf];
  float* obase = out + (((size_t)((b << 14) | (i << 7) | j0)) << 7);
#pragma unroll
  for (int reg = 0; reg < 4; ++reg) {
    float* r = obase + (size_t)(m * 16 + q4 * 4 + reg) * 128;
    r[f0 + colf] = a0[reg] + cb0s;
    r[f0 + 16 + colf] = a1[reg] + cb1s;
  }
}

extern "C" void kernel_launch(void* const* d_in, const int* in_sizes, int n_in,
                              void* d_out, int out_size, void* d_ws, size_t ws_size,
                              hipStream_t stream) {
  const float* x = (const float*)d_in[0];
  const float* oW = (const float*)d_in[1];
  const float* ob = (const float*)d_in[2];
  const float* cW = (const float*)d_in[3];
  const float* cb = (const float*)d_in[4];
  float* out = (float*)d_out;

  if (ws_size >= WS_NEED) {
    unsigned short* cWb = (unsigned short*)d_ws;
    float* oWt = (float*)((char*)d_ws + OWT_OFF);
    hipLaunchKernelGGL(pack_kernel, dim3(288), dim3(256), 0, stream,
                       cW, oW, cWb, oWt);
    hipLaunchKernelGGL(fused_kernel, dim3(2048), dim3(512), 0, stream,
                       x, oWt, ob, cb, out, cWb);
  } else {
    hipLaunchKernelGGL(fused_deform_kernel, dim3(4096), dim3(512), 0, stream,
                       x, oW, ob, cW, cb, out);
  }
}